// Round 3
// baseline (11692.092 us; speedup 1.0000x reference)
//
#include <hip/hip_runtime.h>
#include <math.h>

// Fixed topology
#define BB 64
#define TT 512
#define II 256
#define HH 512
#define OO 256
#define MM 256
#define BT (BB*TT)

// ---- workspace layout (float offsets) ----
// UA  : (B,T,768) rows = [U1(512) | U0(256)] before step t, overwritten with
//       [v1_t(512) | mem_t(256)] during step t (consumed-then-overwritten).
// W1R : A1 swizzled for rnn phase 1 (H*M = 131072)
// W2R : [A2|A3] swizzled for rnn phase 2 (M*768 = 196608)
// WYS : y-weights [W12|Wm2] row-major (O*768 = 196608)
// c1, c2, c3
#define OFF_UA  0
#define OFF_W1R (BT*768)
#define OFF_W2R (OFF_W1R + HH*MM)
#define OFF_WYS (OFF_W2R + MM*768)
#define OFF_C1  (OFF_WYS + OO*768)
#define OFF_C2  (OFF_C1 + HH)
#define OFF_C3  (OFF_C2 + OO)
#define WS_FLOATS (OFF_C3 + MM)
// total 25,691,136 floats = 102.76 MB (same as round-2 layout, which passed)

// phase-1 weight swizzle: A1[h][k], h in [0,512), k in [0,256).
// thread t=(q<<1)|s owns h-pair {2q, 2q+1} over k-range [128s,128s+128).
// reg slot j = (r<<5)|jj : r = h&1 (r=0 -> register-resident, r=1 -> streamed),
// jj = (k&127)>>2.  layout: [j][t] float4.
__device__ __forceinline__ int w1r_index(int h, int k) {
    int q = h >> 1, r = h & 1;
    int s = k >> 7, jj = (k & 127) >> 2, e = k & 3;
    int t = (q << 1) | s;
    int j = (r << 5) | jj;
    return OFF_W1R + (j*512 + t)*4 + e;
}
// phase-2 weight swizzle: A23[m][k], k in [0,768) = [A2(512) | A3(256)].
// thread t=(m<<1)|s owns output m over k-range [384s,384s+384); slot jj=(k-384s)>>2.
__device__ __forceinline__ int w2r_index(int m, int k) {
    int s = k / 384, jj = (k - 384*s) >> 2, e = k & 3;
    int t = (m << 1) | s;
    return OFF_W2R + (jj*512 + t)*4 + e;
}

// c1 = W01@bm0 + b01 + bm1 ; c2 = b12+bm2 ; c3 = W0m@bm0 + W2m@c2 + b0m+b1m+b2m
__global__ void pre_vecs(const float* __restrict__ W01, const float* __restrict__ b01,
                         const float* __restrict__ b12, const float* __restrict__ bm0,
                         const float* __restrict__ bm1, const float* __restrict__ bm2,
                         const float* __restrict__ W0m, const float* __restrict__ b0m,
                         const float* __restrict__ b1m, const float* __restrict__ b2m,
                         const float* __restrict__ W2m, float* __restrict__ ws) {
    int id = blockIdx.x*256 + threadIdx.x;
    if (id < HH) {
        float acc = b01[id] + bm1[id];
        for (int i = 0; i < II; ++i) acc += W01[id*II + i] * bm0[i];
        ws[OFF_C1 + id] = acc;
    } else if (id < HH + OO) {
        int m = id - HH;
        ws[OFF_C2 + m] = b12[m] + bm2[m];
        float acc = b0m[m] + b1m[m] + b2m[m];
        for (int i = 0; i < II; ++i) acc += W0m[m*II + i] * bm0[i];
        for (int o = 0; o < OO; ++o) acc += W2m[m*OO + o] * (b12[o] + bm2[o]);
        ws[OFF_C3 + m] = acc;
    }
}

// A1 = W01@Wm0 + Wm1. grid 512 (h) x 256 (k)
__global__ void make_W1R(const float* __restrict__ W01, const float* __restrict__ Wm0,
                         const float* __restrict__ Wm1, float* __restrict__ ws) {
    int h = blockIdx.x, k = threadIdx.x;
    float acc = Wm1[h*MM + k];
    for (int i = 0; i < II; ++i) acc += W01[h*II + i] * Wm0[i*MM + k];
    ws[w1r_index(h, k)] = acc;
}
// A2 = W1m + W2m@W12. grid 256 (m) x 512 (k=h)
__global__ void make_A2(const float* __restrict__ W1m, const float* __restrict__ W2m,
                        const float* __restrict__ W12, float* __restrict__ ws) {
    int m = blockIdx.x, h = threadIdx.x;
    float acc = W1m[m*HH + h];
    for (int o = 0; o < OO; ++o) acc += W2m[m*OO + o] * W12[o*HH + h];
    ws[w2r_index(m, h)] = acc;
}
// A3 = W0m@Wm0 + W2m@Wm2. grid 256 (m) x 256 (m2)
__global__ void make_A3(const float* __restrict__ W0m, const float* __restrict__ Wm0,
                        const float* __restrict__ W2m, const float* __restrict__ Wm2,
                        float* __restrict__ ws) {
    int m = blockIdx.x, m2 = threadIdx.x;
    float acc = 0.f;
    for (int i = 0; i < II; ++i) acc += W0m[m*II + i] * Wm0[i*MM + m2];
    for (int o = 0; o < OO; ++o) acc += W2m[m*OO + o] * Wm2[o*MM + m2];
    ws[w2r_index(m, 512 + m2)] = acc;
}
// WYS[o][768] = [W12 row | Wm2 row] plain row-major. grid 256 (o) x 768 (k)
__global__ void make_WYS(const float* __restrict__ W12, const float* __restrict__ Wm2,
                         float* __restrict__ ws) {
    int o = blockIdx.x, k = threadIdx.x;
    ws[OFF_WYS + o*768 + k] = (k < HH) ? W12[o*HH + k] : Wm2[o*MM + (k - HH)];
}

// out[n][c] = sum_k x[n][k]*W[c][k] + cvec[c]. 64x64 tile, 4x4 per thread.
// ld* in float4 units. Used for U1/U0 precompute (K4=64) and deferred y (K4=192).
template<int K4>
__global__ __launch_bounds__(256)
void gemm_nt(const float* __restrict__ x, int ldx4,
             const float* __restrict__ W, int ldw4,
             const float* __restrict__ cvec,
             float* __restrict__ out, int ldo4) {
    const int tid = threadIdx.x;
    const int tx = tid & 15, ty = tid >> 4;
    const int n0 = blockIdx.x * 64 + 4*ty;
    const int c0 = blockIdx.y * 64 + 4*tx;
    const float4* x4 = reinterpret_cast<const float4*>(x) + (size_t)n0*ldx4;
    const float4* W4 = reinterpret_cast<const float4*>(W) + (size_t)c0*ldw4;
    float acc[4][4] = {};
    #pragma unroll 4
    for (int k4 = 0; k4 < K4; ++k4) {
        float4 a[4], w[4];
        #pragma unroll
        for (int r = 0; r < 4; ++r) a[r] = x4[(size_t)r*ldx4 + k4];
        #pragma unroll
        for (int c = 0; c < 4; ++c) w[c] = W4[(size_t)c*ldw4 + k4];
        #pragma unroll
        for (int r = 0; r < 4; ++r)
            #pragma unroll
            for (int c = 0; c < 4; ++c)
                acc[r][c] += a[r].x*w[c].x + a[r].y*w[c].y + a[r].z*w[c].z + a[r].w*w[c].w;
    }
    #pragma unroll
    for (int r = 0; r < 4; ++r) {
        float4 o;
        o.x = acc[r][0] + cvec[c0+0];
        o.y = acc[r][1] + cvec[c0+1];
        o.z = acc[r][2] + cvec[c0+2];
        o.w = acc[r][3] + cvec[c0+3];
        reinterpret_cast<float4*>(out)[(size_t)(n0 + r)*ldo4 + (c0>>2)] = o;
    }
}

__device__ __forceinline__ float dot4(float4 w, float4 a) {
    return w.x*a.x + w.y*a.y + w.z*a.z + w.w*a.w;
}

// ---- main persistent recurrent kernel ----
// grid = 64 (one block per batch row), 512 threads (8 waves, 2/SIMD, <=256 VGPR).
// thread t: s=t&1 (k-half), q=t>>1.
// phase 1: h-pair {2q,2q+1} over k-half of mem; A1 even rows in 128 VGPRs, odd rows streamed.
// phase 2: mem'[q] over k-range [384s,384s+384); first 16 float4/thread (128 KB) LDS-resident.
// y deferred: [v1|mem] stored into UA row t (3 KB/step; write port, not read port).
// LDS act buf pad-swizzle: addr(k) = k + 4*(k>>6).
__global__ __launch_bounds__(512, 2)
void rnn_main(float* __restrict__ ws, float* __restrict__ out) {
    __shared__ float buf[2][816];
    __shared__ float4 lds_w[16*512];   // 128 KB of A23 (jj < 16)
    const int tid = threadIdx.x;
    const int b = blockIdx.x;
    const int s = tid & 1;
    const int q = tid >> 1;
    const bool lead = (s == 0);

    const float4* W1R4 = reinterpret_cast<const float4*>(ws + OFF_W1R);
    const float4* W2R4 = reinterpret_cast<const float4*>(ws + OFF_W2R);
    float* UAb = ws + OFF_UA + (size_t)b*TT*768;

    float4 w1reg[32];                  // A1 even rows: 128 VGPRs
    #pragma unroll
    for (int j = 0; j < 32; ++j) w1reg[j] = W1R4[j*512 + tid];
    #pragma unroll
    for (int j = 0; j < 16; ++j) lds_w[j*512 + tid] = W2R4[j*512 + tid];
    if (tid < 256) { int k = 512 + tid; buf[0][k + ((k>>6)<<2)] = 0.f; }
    __syncthreads();

    for (int t = 0; t < TT; ++t) {
        const int p = t & 1;
        const float4* bufp4 = reinterpret_cast<const float4*>(buf[p]);
        float* row = UAb + (size_t)t*768;

        // ---- phase 1: v1 = act(U1 + mem @ A1^T) ----
        // u1/u0 MUST load before the barrier: phase 2 overwrites this UA row.
        float2 u1 = make_float2(0.f, 0.f);
        float u0 = 0.f;
        if (lead) {
            u1 = *reinterpret_cast<const float2*>(row + tid);   // h0 = tid (even)
            u0 = row[512 + q];
        }
        float a0 = 0.f, a1 = 0.f;
        #pragma unroll
        for (int jj = 0; jj < 32; ++jj) {
            float4 a  = bufp4[136 + 34*s + jj + (jj>>4)];       // mem k-half
            float4 w1 = W1R4[(32 + jj)*512 + tid];              // odd row (streamed)
            a0 += dot4(w1reg[jj], a);
            a1 += dot4(w1, a);
        }
        a0 += __shfl_xor(a0, 1);
        a1 += __shfl_xor(a1, 1);
        if (lead) {
            float v0 = a0 + u1.x, v1v = a1 + u1.y;
            if (tid < 256) { v0 = fmaxf(v0, 0.f); v1v = fmaxf(v1v, 0.f); }  // wave-uniform
            else           { v0 = tanhf(v0);      v1v = tanhf(v1v); }
            int ai = tid + ((tid>>6)<<2);
            *reinterpret_cast<float2*>(&buf[p][ai]) = make_float2(v0, v1v);
        }
        __syncthreads();

        // ---- phase 2: mem' = U0 + [v1|mem] @ A23^T ; store [v1|mem] for y ----
        float am0 = 0.f, am1 = 0.f;
        #pragma unroll
        for (int jj = 0; jj < 16; ++jj) {                        // LDS-resident part
            float4 a = bufp4[102*s + jj];
            float4 w = lds_w[jj*512 + tid];
            if (jj & 1) am1 += dot4(w, a); else am0 += dot4(w, a);
        }
        if (tid < 384) {                                         // act row -> UA (for y-GEMM)
            int k2 = 2*tid;
            float2 v = *reinterpret_cast<const float2*>(&buf[p][k2 + ((k2>>6)<<2)]);
            *reinterpret_cast<float2*>(row + k2) = v;
        }
        #pragma unroll 8
        for (int jj = 16; jj < 96; ++jj) {                       // streamed part
            float4 a = bufp4[102*s + jj + (jj>>4)];
            float4 w = W2R4[jj*512 + tid];
            if (jj & 1) am1 += dot4(w, a); else am0 += dot4(w, a);
        }
        float am = am0 + am1;
        am += __shfl_xor(am, 1);
        if (lead) {
            float mv = am + u0;
            int k = 512 + q;
            buf[p^1][k + ((k>>6)<<2)] = mv;
            if (t == TT-1) out[(size_t)BT*OO + b*MM + q] = mv;
        }
        __syncthreads();
    }
}

extern "C" void kernel_launch(void* const* d_in, const int* in_sizes, int n_in,
                              void* d_out, int out_size, void* d_ws, size_t ws_size,
                              hipStream_t stream) {
    const float* inputs = (const float*)d_in[0];
    const float* W01 = (const float*)d_in[1];  const float* b01 = (const float*)d_in[2];
    const float* W12 = (const float*)d_in[3];  const float* b12 = (const float*)d_in[4];
    const float* Wm0 = (const float*)d_in[5];  const float* bm0 = (const float*)d_in[6];
    const float* Wm1 = (const float*)d_in[7];  const float* bm1 = (const float*)d_in[8];
    const float* Wm2 = (const float*)d_in[9];  const float* bm2 = (const float*)d_in[10];
    const float* W0m = (const float*)d_in[11]; const float* b0m = (const float*)d_in[12];
    const float* W1m = (const float*)d_in[13]; const float* b1m = (const float*)d_in[14];
    const float* W2m = (const float*)d_in[15]; const float* b2m = (const float*)d_in[16];
    float* outf = (float*)d_out;
    float* wsf = (float*)d_ws;

    // OOB guard (round-2 layout passed with the same byte count)
    if (ws_size < (size_t)WS_FLOATS * sizeof(float)) return;

    // fused-weight / bias precompute
    pre_vecs<<<3, 256, 0, stream>>>(W01, b01, b12, bm0, bm1, bm2, W0m, b0m, b1m, b2m, W2m, wsf);
    make_W1R<<<HH, 256, 0, stream>>>(W01, Wm0, Wm1, wsf);
    make_A2<<<MM, 512, 0, stream>>>(W1m, W2m, W12, wsf);
    make_A3<<<MM, 256, 0, stream>>>(W0m, Wm0, W2m, Wm2, wsf);
    make_WYS<<<OO, 768, 0, stream>>>(W12, Wm2, wsf);
    // input projections into UA rows: [U1(512) | U0(256)]
    gemm_nt<64><<<dim3(BT/64, HH/64), 256, 0, stream>>>(inputs, 64, W01, 64, wsf + OFF_C1, wsf + OFF_UA, 192);
    gemm_nt<64><<<dim3(BT/64, MM/64), 256, 0, stream>>>(inputs, 64, W0m, 64, wsf + OFF_C3, wsf + OFF_UA + 512, 192);
    // recurrent sweep (writes [v1|mem] back into UA rows)
    rnn_main<<<BB, 512, 0, stream>>>(wsf, outf);
    // deferred y = [v1|mem] @ [W12|Wm2]^T + c2 over all (b,t)
    gemm_nt<192><<<dim3(BT/64, OO/64), 256, 0, stream>>>(wsf + OFF_UA, 192, wsf + OFF_WYS, 192, wsf + OFF_C2, outf, 64);
}

// Round 4
// 6255.079 us; speedup vs baseline: 1.8692x; 1.8692x over previous
//
#include <hip/hip_runtime.h>
#include <math.h>

// Fixed topology
#define BB 64
#define TT 512
#define II 256
#define HH 512
#define OO 256
#define MM 256
#define BT (BB*TT)

// ---- workspace layout (float offsets) ----
// UA  : (B,T,768) rows = [U1(512) | U0(256)] before step t, overwritten with
//       [v1_t(512) | mem_t(256)] during step t (consumed-then-overwritten).
// W1S : A1 swizzled for rnn phase 1 (H*M = 131072)   [round-2 proven layout]
// W2R : [A2|A3] swizzled for rnn phase 2 (M*768 = 196608)
// WYS : y-weights [W12|Wm2] row-major (O*768 = 196608)
// c1, c2, c3
#define OFF_UA  0
#define OFF_W1S (BT*768)
#define OFF_W2R (OFF_W1S + HH*MM)
#define OFF_WYS (OFF_W2R + MM*768)
#define OFF_C1  (OFF_WYS + OO*768)
#define OFF_C2  (OFF_C1 + HH)
#define OFF_C3  (OFF_C2 + OO)
#define WS_FLOATS (OFF_C3 + MM)
// total 25,691,136 floats = 102.76 MB (same byte count as rounds 2/3, which passed)

// phase-1 weight swizzle (round-2 proven): A1[h][k], h in [0,512), k in [0,256).
// thread tid=(q<<2)|ks owns h-pair {2q,2q+1} over k-slice [64ks, 64ks+64).
// slot j=(k&63)>>2; row parity r=h&1; layout [(2j+r)][tid] float4.
__device__ __forceinline__ int w1s_index(int h, int k) {
    int p = h >> 1, r = h & 1;
    int ks = k >> 6, rem = k & 63;
    int j = rem >> 2, e = rem & 3;
    int tid = (p << 2) | ks;
    return OFF_W1S + ((j*2 + r)*1024 + tid)*4 + e;
}
// phase-2 weight swizzle: A23[m][k], k in [0,768) = [A2(512) | A3(256)].
// thread tid=(m<<2)|ks owns output m over k-slice [192ks, 192ks+192).
// slot jj=(k-192ks)>>2 in [0,48); layout [jj][tid] float4.
__device__ __forceinline__ int w2r_index(int m, int k) {
    int ks = k / 192, jj = (k - 192*ks) >> 2, e = k & 3;
    int tid = (m << 2) | ks;
    return OFF_W2R + (jj*1024 + tid)*4 + e;
}

// c1 = W01@bm0 + b01 + bm1 ; c2 = b12+bm2 ; c3 = W0m@bm0 + W2m@c2 + b0m+b1m+b2m
__global__ void pre_vecs(const float* __restrict__ W01, const float* __restrict__ b01,
                         const float* __restrict__ b12, const float* __restrict__ bm0,
                         const float* __restrict__ bm1, const float* __restrict__ bm2,
                         const float* __restrict__ W0m, const float* __restrict__ b0m,
                         const float* __restrict__ b1m, const float* __restrict__ b2m,
                         const float* __restrict__ W2m, float* __restrict__ ws) {
    int id = blockIdx.x*256 + threadIdx.x;
    if (id < HH) {
        float acc = b01[id] + bm1[id];
        for (int i = 0; i < II; ++i) acc += W01[id*II + i] * bm0[i];
        ws[OFF_C1 + id] = acc;
    } else if (id < HH + OO) {
        int m = id - HH;
        ws[OFF_C2 + m] = b12[m] + bm2[m];
        float acc = b0m[m] + b1m[m] + b2m[m];
        for (int i = 0; i < II; ++i) acc += W0m[m*II + i] * bm0[i];
        for (int o = 0; o < OO; ++o) acc += W2m[m*OO + o] * (b12[o] + bm2[o]);
        ws[OFF_C3 + m] = acc;
    }
}

// A1 = W01@Wm0 + Wm1. grid 512 (h) x 256 (k)
__global__ void make_W1S(const float* __restrict__ W01, const float* __restrict__ Wm0,
                         const float* __restrict__ Wm1, float* __restrict__ ws) {
    int h = blockIdx.x, k = threadIdx.x;
    float acc = Wm1[h*MM + k];
    for (int i = 0; i < II; ++i) acc += W01[h*II + i] * Wm0[i*MM + k];
    ws[w1s_index(h, k)] = acc;
}
// A2 = W1m + W2m@W12. grid 256 (m) x 512 (k=h)
__global__ void make_A2(const float* __restrict__ W1m, const float* __restrict__ W2m,
                        const float* __restrict__ W12, float* __restrict__ ws) {
    int m = blockIdx.x, h = threadIdx.x;
    float acc = W1m[m*HH + h];
    for (int o = 0; o < OO; ++o) acc += W2m[m*OO + o] * W12[o*HH + h];
    ws[w2r_index(m, h)] = acc;
}
// A3 = W0m@Wm0 + W2m@Wm2. grid 256 (m) x 256 (m2): k = 512+m2
__global__ void make_A3(const float* __restrict__ W0m, const float* __restrict__ Wm0,
                        const float* __restrict__ W2m, const float* __restrict__ Wm2,
                        float* __restrict__ ws) {
    int m = blockIdx.x, m2 = threadIdx.x;
    float acc = 0.f;
    for (int i = 0; i < II; ++i) acc += W0m[m*II + i] * Wm0[i*MM + m2];
    for (int o = 0; o < OO; ++o) acc += W2m[m*OO + o] * Wm2[o*MM + m2];
    ws[w2r_index(m, 512 + m2)] = acc;
}
// WYS[o][768] = [W12 row | Wm2 row] plain row-major. grid 256 (o) x 768 (k)
__global__ void make_WYS(const float* __restrict__ W12, const float* __restrict__ Wm2,
                         float* __restrict__ ws) {
    int o = blockIdx.x, k = threadIdx.x;
    ws[OFF_WYS + o*768 + k] = (k < HH) ? W12[o*HH + k] : Wm2[o*MM + (k - HH)];
}

// out[n][c] = sum_k x[n][k]*W[c][k] + cvec[c]. 64x64 tile, 4x4 per thread.
// ld* in float4 units. Used for U1/U0 precompute (K4=64) and deferred y (K4=192).
template<int K4>
__global__ __launch_bounds__(256)
void gemm_nt(const float* __restrict__ x, int ldx4,
             const float* __restrict__ W, int ldw4,
             const float* __restrict__ cvec,
             float* __restrict__ out, int ldo4) {
    const int tid = threadIdx.x;
    const int tx = tid & 15, ty = tid >> 4;
    const int n0 = blockIdx.x * 64 + 4*ty;
    const int c0 = blockIdx.y * 64 + 4*tx;
    const float4* x4 = reinterpret_cast<const float4*>(x) + (size_t)n0*ldx4;
    const float4* W4 = reinterpret_cast<const float4*>(W) + (size_t)c0*ldw4;
    float acc[4][4] = {};
    #pragma unroll 4
    for (int k4 = 0; k4 < K4; ++k4) {
        float4 a[4], w[4];
        #pragma unroll
        for (int r = 0; r < 4; ++r) a[r] = x4[(size_t)r*ldx4 + k4];
        #pragma unroll
        for (int c = 0; c < 4; ++c) w[c] = W4[(size_t)c*ldw4 + k4];
        #pragma unroll
        for (int r = 0; r < 4; ++r)
            #pragma unroll
            for (int c = 0; c < 4; ++c)
                acc[r][c] += a[r].x*w[c].x + a[r].y*w[c].y + a[r].z*w[c].z + a[r].w*w[c].w;
    }
    #pragma unroll
    for (int r = 0; r < 4; ++r) {
        float4 o;
        o.x = acc[r][0] + cvec[c0+0];
        o.y = acc[r][1] + cvec[c0+1];
        o.z = acc[r][2] + cvec[c0+2];
        o.w = acc[r][3] + cvec[c0+3];
        reinterpret_cast<float4*>(out)[(size_t)(n0 + r)*ldo4 + (c0>>2)] = o;
    }
}

__device__ __forceinline__ float dot4(float4 w, float4 a) {
    return w.x*a.x + w.y*a.y + w.z*a.z + w.w*a.w;
}

// ---- main persistent recurrent kernel ----
// grid = 64 (one block per batch row), 1024 threads (16 waves, 4/SIMD — the
// round-2 config that sustained ~54 B/cy per-CU L2 read).
// thread tid: q=tid>>2 (output id), ks=tid&3 (k-slice id).
// phase 1: h-pair {2q,2q+1} over mem k-slice; first 4 slot-pairs (8 float4 =
//          32 VGPR) register-resident, remaining 24 slots streamed from L2.
// phase 2: mem'[q] over [v1|mem] k-slice; first 8 slots (128 KB) LDS-resident,
//          remaining 40 slots streamed.
// y deferred: [v1|mem] written into the consumed UA row (write port, not read).
// LDS act buf pad-swizzle: addr(k) = k + 4*(k>>6). Proven zero-conflict.
__global__ __launch_bounds__(1024, 4)
void rnn_main(float* __restrict__ ws, float* __restrict__ out) {
    __shared__ float buf[2][816];
    __shared__ float4 lds_w[8*1024];   // 128 KB of A23 (jj < 8)
    const int tid = threadIdx.x;
    const int b = blockIdx.x;
    const int q = tid >> 2;
    const int ks = tid & 3;
    const bool lead = (ks == 0);

    const float4* W1S4 = reinterpret_cast<const float4*>(ws + OFF_W1S);
    const float4* W2R4 = reinterpret_cast<const float4*>(ws + OFF_W2R);
    float* UAb = ws + OFF_UA + (size_t)b*TT*768;

    float4 w1e[4], w1o[4];             // A1 slots j=0..3, both rows: 32 VGPRs
    #pragma unroll
    for (int j = 0; j < 4; ++j) {
        w1e[j] = W1S4[(2*j)*1024 + tid];
        w1o[j] = W1S4[(2*j+1)*1024 + tid];
    }
    #pragma unroll
    for (int j = 0; j < 8; ++j) lds_w[j*1024 + tid] = W2R4[j*1024 + tid];
    if (tid < 256) { int k = 512 + tid; buf[0][k + ((k>>6)<<2)] = 0.f; }
    __syncthreads();

    for (int t = 0; t < TT; ++t) {
        const int p = t & 1;
        const float4* bufp4 = reinterpret_cast<const float4*>(buf[p]);
        float* row = UAb + (size_t)t*768;

        // ---- phase 1: v1 = act(U1 + mem @ A1^T) ----
        // u1/u0 loaded here (before this UA row is overwritten in phase 2);
        // the vmcnt(0) drain at the phase-1 barrier guarantees they land first.
        float2 u1 = make_float2(0.f, 0.f);
        float u0 = 0.f;
        if (lead) {
            u1 = *reinterpret_cast<const float2*>(row + 2*q);
            u0 = row[512 + q];
        }
        float a0 = 0.f, a1 = 0.f;
        #pragma unroll
        for (int j = 0; j < 4; ++j) {                        // register-resident part
            float4 a = bufp4[136 + 17*ks + j];
            a0 += dot4(w1e[j], a);
            a1 += dot4(w1o[j], a);
        }
        #pragma unroll 4
        for (int j = 4; j < 16; ++j) {                       // streamed part
            float4 a  = bufp4[136 + 17*ks + j];
            float4 we = W1S4[(2*j)*1024 + tid];
            float4 wo = W1S4[(2*j+1)*1024 + tid];
            a0 += dot4(we, a);
            a1 += dot4(wo, a);
        }
        a0 += __shfl_xor(a0, 1); a0 += __shfl_xor(a0, 2);
        a1 += __shfl_xor(a1, 1); a1 += __shfl_xor(a1, 2);
        if (lead) {
            int h0 = 2*q;
            float v0 = a0 + u1.x, v1v = a1 + u1.y;
            if (h0 < 256) { v0 = fmaxf(v0, 0.f); v1v = fmaxf(v1v, 0.f); }  // wave-uniform
            else          { v0 = tanhf(v0);      v1v = tanhf(v1v); }
            int ai = h0 + ((h0>>6)<<2);
            *reinterpret_cast<float2*>(&buf[p][ai]) = make_float2(v0, v1v);
        }
        __syncthreads();

        // ---- phase 2: mem' = U0 + [v1|mem] @ A23^T ; store [v1|mem] for y ----
        float am = 0.f;
        #pragma unroll
        for (int jj = 0; jj < 8; ++jj) {                     // LDS-resident part
            float4 a = bufp4[51*ks + jj];
            am += dot4(lds_w[jj*1024 + tid], a);
        }
        if (tid < 384) {                                     // act row -> UA (for y-GEMM)
            int k2 = 2*tid;
            float2 v = *reinterpret_cast<const float2*>(&buf[p][k2 + ((k2>>6)<<2)]);
            *reinterpret_cast<float2*>(row + k2) = v;
        }
        #pragma unroll 4
        for (int jj = 8; jj < 48; ++jj) {                    // streamed part
            float4 a = bufp4[51*ks + jj + (jj>>4)];
            am += dot4(W2R4[jj*1024 + tid], a);
        }
        am += __shfl_xor(am, 1); am += __shfl_xor(am, 2);
        if (lead) {
            float mv = am + u0;
            int k = 512 + q;
            buf[p^1][k + ((k>>6)<<2)] = mv;
            if (t == TT-1) out[(size_t)BT*OO + b*MM + q] = mv;
        }
        __syncthreads();
    }
}

extern "C" void kernel_launch(void* const* d_in, const int* in_sizes, int n_in,
                              void* d_out, int out_size, void* d_ws, size_t ws_size,
                              hipStream_t stream) {
    const float* inputs = (const float*)d_in[0];
    const float* W01 = (const float*)d_in[1];  const float* b01 = (const float*)d_in[2];
    const float* W12 = (const float*)d_in[3];  const float* b12 = (const float*)d_in[4];
    const float* Wm0 = (const float*)d_in[5];  const float* bm0 = (const float*)d_in[6];
    const float* Wm1 = (const float*)d_in[7];  const float* bm1 = (const float*)d_in[8];
    const float* Wm2 = (const float*)d_in[9];  const float* bm2 = (const float*)d_in[10];
    const float* W0m = (const float*)d_in[11]; const float* b0m = (const float*)d_in[12];
    const float* W1m = (const float*)d_in[13]; const float* b1m = (const float*)d_in[14];
    const float* W2m = (const float*)d_in[15]; const float* b2m = (const float*)d_in[16];
    float* outf = (float*)d_out;
    float* wsf = (float*)d_ws;

    // OOB guard (same byte count as rounds 2/3, which passed)
    if (ws_size < (size_t)WS_FLOATS * sizeof(float)) return;

    // fused-weight / bias precompute
    pre_vecs<<<3, 256, 0, stream>>>(W01, b01, b12, bm0, bm1, bm2, W0m, b0m, b1m, b2m, W2m, wsf);
    make_W1S<<<HH, 256, 0, stream>>>(W01, Wm0, Wm1, wsf);
    make_A2<<<MM, 512, 0, stream>>>(W1m, W2m, W12, wsf);
    make_A3<<<MM, 256, 0, stream>>>(W0m, Wm0, W2m, Wm2, wsf);
    make_WYS<<<OO, 768, 0, stream>>>(W12, Wm2, wsf);
    // input projections into UA rows: [U1(512) | U0(256)]
    gemm_nt<64><<<dim3(BT/64, HH/64), 256, 0, stream>>>(inputs, 64, W01, 64, wsf + OFF_C1, wsf + OFF_UA, 192);
    gemm_nt<64><<<dim3(BT/64, MM/64), 256, 0, stream>>>(inputs, 64, W0m, 64, wsf + OFF_C3, wsf + OFF_UA + 512, 192);
    // recurrent sweep (writes [v1|mem] back into UA rows)
    rnn_main<<<BB, 1024, 0, stream>>>(wsf, outf);
    // deferred y = [v1|mem] @ [W12|Wm2]^T + c2 over all (b,t)
    gemm_nt<192><<<dim3(BT/64, OO/64), 256, 0, stream>>>(wsf + OFF_UA, 192, wsf + OFF_WYS, 192, wsf + OFF_C2, outf, 64);
}